// Round 17
// baseline (351.603 us; speedup 1.0000x reference)
//
#include <hip/hip_runtime.h>
#include <stdint.h>

// Binary BasicBlock: x ->(sign) conv1 ->BN1 ->(sign) conv2 ->BN2 -> +x
// B=64, C=256, H=W=28.  M = 64*784 = 50176 output pixels, N = 256, K = 9*256.
// Convs as exact i8 MFMA implicit-GEMM (binarized {-1,0,1}, int accum <= 2304
// -> bit-exact vs f32). Conv biases cancel in training-mode BN -> dropped.
//
// R17: conv reverted to R6 VERBATIM geometry (best of 12 structural attempts;
// R16's residency-round theory refuted: occupancy 13->21% with MfmaUtil flat).
// New: bn_params FUSED into conv's last block (fused final reduction) —
// stats via 32-bucket ull atomics + completion counter; last block computes
// mean/inv for all 256 channels, re-zeros state for graph replay. Pipeline
// is 5 dispatches: prep -> conv1 -> bin_mid -> conv2 -> bn_residual.
// Tail kernels = R15 (near BW floor).

#define HW    784
#define MTOT  50176
#define BM    128
#define BN    128
#define NBLK  784          // (MTOT/128) * (256/128)

typedef int   i32x4  __attribute__((ext_vector_type(4)));
typedef int   int4v  __attribute__((ext_vector_type(4)));
typedef short shortx8 __attribute__((ext_vector_type(8)));
typedef float floatx4 __attribute__((ext_vector_type(4)));
typedef unsigned long long ull;

typedef __attribute__((address_space(1))) const void gvoid_t;
typedef __attribute__((address_space(3))) void       lvoid_t;

__device__ __forceinline__ void gload16(const void* g, void* l) {
  // async global->LDS, 16B/lane; LDS dest = wave-uniform base + lane*16
  __builtin_amdgcn_global_load_lds((gvoid_t*)g, (lvoid_t*)l, 16, 0, 0);
}

#define BAR() __builtin_amdgcn_s_barrier()
#define VM8() asm volatile("s_waitcnt vmcnt(8)" ::: "memory")
#define VM0() asm volatile("s_waitcnt vmcnt(0)" ::: "memory")

// ---------------------------------------------------------------- prep
// bid 0: zero page + stats buckets + counters; 1..512: w binarize
// (one n-row per block, LDS-staged); 513..3648: bin_x transpose.
__global__ __launch_bounds__(256) void prep(const float* __restrict__ w1,
                                            const float* __restrict__ w2,
                                            int8_t* __restrict__ wb1,
                                            int8_t* __restrict__ wb2,
                                            floatx4* __restrict__ zp,
                                            int4v* __restrict__ statsz, // 262144B
                                            unsigned* __restrict__ ctrs,
                                            const float* __restrict__ x,
                                            int8_t* __restrict__ xb) {
  const int bid = blockIdx.x;
  const int t = threadIdx.x;
  if (bid == 0) {
    zp[t] = (floatx4){0.f, 0.f, 0.f, 0.f};
#pragma unroll
    for (int k = 0; k < 64; ++k) statsz[t + k * 256] = (int4v){0, 0, 0, 0};
    if (t < 2) ctrs[t] = 0;
    return;
  }
  if (bid < 513) {
    // w OIHW [256][256][3][3] -> wb [n][k], k = tap*256 + c (tap = ky*3+kx).
    int base = bid - 1;                        // 0..511
    const float* w = (base < 256) ? w1 : w2;
    int8_t* wbp = (base < 256) ? wb1 : wb2;
    int n = base & 255;
    __shared__ float wl[2304];
    for (int i = t; i < 2304; i += 256) wl[i] = w[(size_t)n * 2304 + i];
    __syncthreads();
    for (int s = t; s < 288; s += 256) {
      union { int8_t b8[8]; ull u; } o;
#pragma unroll
      for (int j = 0; j < 8; ++j) {
        int k = s * 8 + j;
        float v = wl[(k & 255) * 9 + (k >> 8)];
        o.b8[j] = (int8_t)((v > 0.f) - (v < 0.f));
      }
      ((ull*)(wbp + (size_t)n * 2304))[s] = o.u;
    }
    return;
  }
  // bin_x: LDS transpose tile (64 m x 64 c)
  int idx = bid - 513;                         // < 3136
  const int mt = idx % 784, ct = idx / 784;
  __shared__ int8_t sh[64][68];
  const int tl = t & 63, th = t >> 6;
#pragma unroll
  for (int i = 0; i < 16; ++i) {
    int cl = th + i * 4;
    int c = ct * 64 + cl;
    int m = mt * 64 + tl;
    int b = m / HW, p = m - b * HW;
    float v = x[((size_t)b * 256 + c) * HW + p];   // coalesced along p
    sh[tl][cl] = (int8_t)((v > 0.f) - (v < 0.f));
  }
  __syncthreads();
#pragma unroll
  for (int i = 0; i < 16; ++i) {
    int ml = th + i * 4;
    xb[(size_t)(mt * 64 + ml) * 256 + ct * 64 + tl] = sh[ml][tl];
  }
}

// ---------------------------------------------------------------- conv (MFMA)
// xb [M][256] i8 NHWC, wb [256][2304] i8 -> y [M][256] i16 NHWC
// + stats via 32-bucket ull atomics; last finishing block computes params.
// [conv body R6 VERBATIM — 41.4us, MfmaUtil 26%, 0 bank conflicts]
__global__ __launch_bounds__(256, 2) void bconv_mfma(
    const int8_t* __restrict__ xb, const int8_t* __restrict__ wb,
    int16_t* __restrict__ y, ull* __restrict__ stats,
    unsigned* __restrict__ ctr, const float* __restrict__ gamma,
    float* __restrict__ params, const int8_t* __restrict__ zp) {
  __shared__ int8_t lds[2][32768];              // per buffer A 16KB | B 16KB
  const int tid = threadIdx.x;
  const int lane = tid & 63;
  const int wv = tid >> 6;                      // 4 waves
  const int wm = wv >> 1, wn = wv & 1;          // 2x2 wave grid, 64x64 each
  const int l15 = lane & 15;
  const int l4 = lane >> 4;

  // XCD swizzle: 784 = 8*98 exactly; consecutive mtiles per XCD
  int bid = blockIdx.x;
  int nb = (bid & 7) * (NBLK / 8) + (bid >> 3);
  const int mtile = nb >> 1, ntile = nb & 1;
  const int m0 = mtile * BM, n0 = ntile * BN;

  // staging precompute: call j (0..3), lane's row r = wv*32+j*8+(lane>>3);
  // r&7 == lane>>3 -> pre-swizzle source offset is call-independent.
  // LDS 16B-slot (lane&7) of row r holds global chunk ((lane&7)^(r&7)).
  const int soff = ((lane & 7) ^ (lane >> 3)) << 4;
  int pyv[4], pxv[4], ldso[4];
  size_t pixb[4];
  const int8_t* wsrc[4];
#pragma unroll
  for (int j = 0; j < 4; ++j) {
    int r = wv * 32 + j * 8 + (lane >> 3);
    int m = m0 + r;
    int b = m / HW;
    int p = m - b * HW;
    pyv[j] = p / 28;
    pxv[j] = p - pyv[j] * 28;
    pixb[j] = (size_t)b * HW;
    wsrc[j] = wb + (size_t)(n0 + r) * 2304 + soff;
    ldso[j] = (wv * 32 + j * 8) * 128;          // wave-uniform LDS base
  }

  i32x4 acc[4][4];
#pragma unroll
  for (int a = 0; a < 4; ++a)
#pragma unroll
    for (int b = 0; b < 4; ++b) acc[a][b] = (i32x4){0, 0, 0, 0};

  // unit u = tap*2 + h : tap = u>>1 (0..8), K-half h = u&1 (channel 128-block)
  // STAGE = exactly 8 gload16 per thread (A 4 + B 4) -> vmcnt granularity 8.
  auto STAGE = [&](int8_t* base, int unit) {
    const int tap = unit >> 1;
    const int coff = (unit & 1) << 7;
    const int dy = tap / 3 - 1, dx = tap % 3 - 1;
#pragma unroll
    for (int j = 0; j < 4; ++j) {
      int yy = pyv[j] + dy, xx = pxv[j] + dx;
      const int8_t* sa = ((unsigned)yy < 28u && (unsigned)xx < 28u)
              ? xb + ((pixb[j] + yy * 28 + xx) << 8) + coff + soff
              : zp + soff;
      gload16(sa, base + ldso[j]);                            // A half-tile
      gload16(wsrc[j] + (unit << 7), base + 16384 + ldso[j]); // B half-tile
    }
  };

  auto COMPUTE = [&](const int8_t* base) {
#pragma unroll
    for (int cc = 0; cc < 2; ++cc) {            // K chunks of 64 within half
      i32x4 af[4], bf[4];
      const int bc = cc * 4 + l4;               // 16B block index 0..7
#pragma unroll
      for (int rb = 0; rb < 4; ++rb) {
        int row = wm * 64 + rb * 16 + l15;
        af[rb] = *(const i32x4*)(base + row * 128 + ((bc ^ (row & 7)) << 4));
      }
#pragma unroll
      for (int nf = 0; nf < 4; ++nf) {
        int row = wn * 64 + nf * 16 + l15;
        bf[nf] = *(const i32x4*)(base + 16384 + row * 128 + ((bc ^ (row & 7)) << 4));
      }
      __builtin_amdgcn_s_setprio(1);            // T5: favor MFMA cluster
#pragma unroll
      for (int nf = 0; nf < 4; ++nf)
#pragma unroll
        for (int rb = 0; rb < 4; ++rb)
          acc[nf][rb] = __builtin_amdgcn_mfma_i32_16x16x64_i8(af[rb], bf[nf],
                                                              acc[nf][rb], 0, 0, 0);
      __builtin_amdgcn_s_setprio(0);
    }
  };

  // Counted-vmcnt pipeline (T3+T4): prefetch depth 2, never drain in steady
  // state. Per unit: COMPUTE(u); BAR; STAGE(u+2 into freed buf); VM8; BAR.
  STAGE(lds[0], 0);
  STAGE(lds[1], 1);                             // 16 outstanding
  VM8();                                        // unit 0 landed (in-order)
  BAR();
#pragma unroll
  for (int u = 0; u < 18; u += 2) {
    COMPUTE(lds[0]);                            // unit u
    BAR();                                      // done reading lds[0]
    if (u + 2 < 18) { STAGE(lds[0], u + 2); VM8(); BAR(); }
    else            { VM0(); BAR(); }           // u=16: wait unit 17
    COMPUTE(lds[1]);                            // unit u+1
    BAR();                                      // done reading lds[1]
    if (u + 3 < 18) { STAGE(lds[1], u + 3); VM8(); BAR(); }
  }

  // epilogue: store y (i16 NHWC) + exact per-channel stats via atomics
  int sum_l[4] = {0, 0, 0, 0}, sq_l[4] = {0, 0, 0, 0};
#pragma unroll
  for (int nf = 0; nf < 4; ++nf) {
    const int n = n0 + wn * 64 + nf * 16 + l15;   // C/D: col = lane&15 (m89)
#pragma unroll
    for (int rb = 0; rb < 4; ++rb) {
      const int mb = m0 + wm * 64 + rb * 16 + l4 * 4;  // row = (lane>>4)*4 + j
#pragma unroll
      for (int j = 0; j < 4; ++j) {
        int v = acc[nf][rb][j];
        y[(size_t)(mb + j) * 256 + n] = (int16_t)v;
        sum_l[nf] += v;
        sq_l[nf] += v * v;                        // <= 16*2304^2, fits i32
      }
    }
  }
  const int bucket = bid & 31;
#pragma unroll
  for (int nf = 0; nf < 4; ++nf) {
    int s = sum_l[nf], q = sq_l[nf];
    s += __shfl_xor(s, 16); q += __shfl_xor(q, 16);
    s += __shfl_xor(s, 32); q += __shfl_xor(q, 32);
    if (lane < 16) {
      int n = n0 + wn * 64 + nf * 16 + lane;
      ull* slot = stats + ((size_t)(bucket * 256 + n) << 1);
      atomicAdd(slot, (ull)(long long)s);         // exact: integer wrap-safe
      atomicAdd(slot + 1, (ull)(long long)q);
    }
  }

  // fused final reduction: last finishing block computes BN params.
  __threadfence();                               // stats atomics visible
  __shared__ int islast;
  if (tid == 0) islast = (atomicAdd(ctr, 1u) == NBLK - 1);
  __syncthreads();
  if (islast) {
    __threadfence();
    const int c = tid;                           // one channel per thread
    long long s = 0, q = 0;
#pragma unroll
    for (int k = 0; k < 32; ++k) {
      s += (long long)__hip_atomic_load(stats + ((size_t)(k * 256 + c) << 1),
                                        __ATOMIC_RELAXED, __HIP_MEMORY_SCOPE_AGENT);
      q += (long long)__hip_atomic_load(stats + ((size_t)(k * 256 + c) << 1) + 1,
                                        __ATOMIC_RELAXED, __HIP_MEMORY_SCOPE_AGENT);
    }
    double mean = (double)s / (double)MTOT;
    double var = (double)q / (double)MTOT - mean * mean;
    params[c * 2 + 0] = (float)mean;
    params[c * 2 + 1] = (float)((double)gamma[c] / sqrt(var + 1e-5));
    // re-zero state for the next graph replay (prep also re-zeros)
#pragma unroll
    for (int k = 0; k < 32; ++k) {
      __hip_atomic_store(stats + ((size_t)(k * 256 + c) << 1), 0ull,
                         __ATOMIC_RELAXED, __HIP_MEMORY_SCOPE_AGENT);
      __hip_atomic_store(stats + ((size_t)(k * 256 + c) << 1) + 1, 0ull,
                         __ATOMIC_RELAXED, __HIP_MEMORY_SCOPE_AGENT);
    }
    if (tid == 0)
      __hip_atomic_store(ctr, 0u, __ATOMIC_RELAXED, __HIP_MEMORY_SCOPE_AGENT);
  }
}

// ---------------------------------------------------------------- binarize mid
// xb = sign((y - mean)*inv + beta)   (bias cancels in BN)
__global__ __launch_bounds__(256) void bin_mid(const int16_t* __restrict__ y,
                                               const float* __restrict__ params,
                                               const float* __restrict__ beta,
                                               int8_t* __restrict__ xb) {
  size_t i = ((size_t)blockIdx.x * 256 + threadIdx.x) * 8;
  shortx8 v = *(const shortx8*)(y + i);
  int cb = (int)(i & 255);
  union { int8_t b[8]; ull u; } o;
#pragma unroll
  for (int j = 0; j < 8; ++j) {
    int c = cb + j;
    float z = ((float)v[j] - params[c * 2]) * params[c * 2 + 1] + beta[c];
    o.b[j] = (int8_t)((z > 0.f) - (z < 0.f));
  }
  *(ull*)(xb + i) = o.u;
}

// ---------------------------------------------------------------- BN2 + resid
// out NCHW f32 = (y2 - mean)*inv + beta + x. Thread owns one m x 32-channel
// cache line of y (4x shortx8); params scalar-uniform; x/out lane-coalesced.
__global__ __launch_bounds__(256) void bn_residual(const int16_t* __restrict__ y,
                                                   const float* __restrict__ params,
                                                   const float* __restrict__ beta,
                                                   const float* __restrict__ x,
                                                   float* __restrict__ out) {
  const int t = threadIdx.x;
  const int m = blockIdx.x * 256 + t;
  const int c0 = blockIdx.y * 32;
  const int b = m / HW, p = m - b * HW;
  const int16_t* yp = y + (size_t)m * 256 + c0;
  shortx8 v0 = *(const shortx8*)(yp);
  shortx8 v1 = *(const shortx8*)(yp + 8);
  shortx8 v2 = *(const shortx8*)(yp + 16);
  shortx8 v3 = *(const shortx8*)(yp + 24);
  const size_t xbase = ((size_t)b * 256 + c0) * HW + p;
#pragma unroll
  for (int j = 0; j < 8; ++j) {
#pragma unroll
    for (int g = 0; g < 4; ++g) {
      int c = c0 + g * 8 + j;
      short sv = (g == 0) ? v0[j] : (g == 1) ? v1[j] : (g == 2) ? v2[j] : v3[j];
      float z = ((float)sv - params[c * 2]) * params[c * 2 + 1] + beta[c];
      size_t oi = xbase + (size_t)(g * 8 + j) * HW;
      out[oi] = z + x[oi];
    }
  }
}

// ---------------------------------------------------------------- launch
extern "C" void kernel_launch(void* const* d_in, const int* in_sizes, int n_in,
                              void* d_out, int out_size, void* d_ws, size_t ws_size,
                              hipStream_t stream) {
  const float* x      = (const float*)d_in[0];
  const float* w1     = (const float*)d_in[1];
  const float* gamma1 = (const float*)d_in[3];
  const float* beta1  = (const float*)d_in[4];
  const float* w2     = (const float*)d_in[5];
  const float* gamma2 = (const float*)d_in[7];
  const float* beta2  = (const float*)d_in[8];
  float* out = (float*)d_out;

  // ws layout (bytes):
  char* ws = (char*)d_ws;
  int8_t*   zp      = (int8_t*)ws;                      //        0 : 4096 zero page
  int8_t*   wb1     = (int8_t*)(ws + 4096);             //   589824
  int8_t*   wb2     = (int8_t*)(ws + 593920);           //   589824
  float*    params1 = (float*)(ws + 1183744);           //     2048
  float*    params2 = (float*)(ws + 1185792);           //     2048
  ull*      stats1  = (ull*)(ws + 1187840);             //   131072 (32 buckets)
  ull*      stats2  = (ull*)(ws + 1318912);             //   131072
  unsigned* ctrs    = (unsigned*)(ws + 1449984);        //     4096 (2 used)
  int8_t*   xb      = (int8_t*)(ws + 2793472);          // 12845056 (conv input)
  int16_t*  yb      = (int16_t*)(ws + 15638528);        // 25690112 (y1/y2 reused)
  if (ws_size < 41328640ull) return;                    // need ~39.4 MiB scratch

  prep<<<3649, 256, 0, stream>>>(w1, w2, wb1, wb2, (floatx4*)zp,
                                 (int4v*)stats1, ctrs, x, xb);
  bconv_mfma<<<NBLK, 256, 0, stream>>>(xb, wb1, yb, stats1, ctrs + 0,
                                       gamma1, params1, zp);
  bin_mid<<<6272, 256, 0, stream>>>(yb, params1, beta1, xb);
  bconv_mfma<<<NBLK, 256, 0, stream>>>(xb, wb2, yb, stats2, ctrs + 1,
                                       gamma2, params2, zp);
  bn_residual<<<dim3(196, 8), 256, 0, stream>>>(yb, params2, beta2, x, out);
}

// Round 18
// 327.842 us; speedup vs baseline: 1.0725x; 1.0725x over previous
//
#include <hip/hip_runtime.h>
#include <stdint.h>

// Binary BasicBlock: x ->(sign) conv1 ->BN1 ->(sign) conv2 ->BN2 -> +x
// B=64, C=256, H=W=28.  M = 64*784 = 50176 output pixels, N = 256, K = 9*256.
// Convs as exact i8 MFMA implicit-GEMM (binarized {-1,0,1}, int accum <= 2304
// -> bit-exact vs f32). Conv biases cancel in training-mode BN -> dropped.
//
// R18: R17 fused-bn_params design, LDS-overflow fixed. R17's one-word
// __shared__ int pushed LDS 65536->66048 -> 1 block/CU -> conv 163us.
// Fix: broadcast the islast flag through lds[0][0] (dead after K-loop),
// keeping LDS at exactly 64KB and 2 blocks/CU. Pipeline: 5 dispatches
// (prep -> conv1+params1 -> bin_mid -> conv2+params2 -> bn_residual).

#define HW    784
#define MTOT  50176
#define BM    128
#define BN    128
#define NBLK  784          // (MTOT/128) * (256/128)

typedef int   i32x4  __attribute__((ext_vector_type(4)));
typedef int   int4v  __attribute__((ext_vector_type(4)));
typedef short shortx8 __attribute__((ext_vector_type(8)));
typedef float floatx4 __attribute__((ext_vector_type(4)));
typedef unsigned long long ull;

typedef __attribute__((address_space(1))) const void gvoid_t;
typedef __attribute__((address_space(3))) void       lvoid_t;

__device__ __forceinline__ void gload16(const void* g, void* l) {
  // async global->LDS, 16B/lane; LDS dest = wave-uniform base + lane*16
  __builtin_amdgcn_global_load_lds((gvoid_t*)g, (lvoid_t*)l, 16, 0, 0);
}

#define BAR() __builtin_amdgcn_s_barrier()
#define VM8() asm volatile("s_waitcnt vmcnt(8)" ::: "memory")
#define VM0() asm volatile("s_waitcnt vmcnt(0)" ::: "memory")

// ---------------------------------------------------------------- prep
// bid 0: zero page + stats buckets + counters; 1..512: w binarize
// (one n-row per block, LDS-staged); 513..3648: bin_x transpose.
__global__ __launch_bounds__(256) void prep(const float* __restrict__ w1,
                                            const float* __restrict__ w2,
                                            int8_t* __restrict__ wb1,
                                            int8_t* __restrict__ wb2,
                                            floatx4* __restrict__ zp,
                                            int4v* __restrict__ statsz, // 262144B
                                            unsigned* __restrict__ ctrs,
                                            const float* __restrict__ x,
                                            int8_t* __restrict__ xb) {
  const int bid = blockIdx.x;
  const int t = threadIdx.x;
  if (bid == 0) {
    zp[t] = (floatx4){0.f, 0.f, 0.f, 0.f};
#pragma unroll
    for (int k = 0; k < 64; ++k) statsz[t + k * 256] = (int4v){0, 0, 0, 0};
    if (t < 2) ctrs[t] = 0;
    return;
  }
  if (bid < 513) {
    // w OIHW [256][256][3][3] -> wb [n][k], k = tap*256 + c (tap = ky*3+kx).
    int base = bid - 1;                        // 0..511
    const float* w = (base < 256) ? w1 : w2;
    int8_t* wbp = (base < 256) ? wb1 : wb2;
    int n = base & 255;
    __shared__ float wl[2304];
    for (int i = t; i < 2304; i += 256) wl[i] = w[(size_t)n * 2304 + i];
    __syncthreads();
    for (int s = t; s < 288; s += 256) {
      union { int8_t b8[8]; ull u; } o;
#pragma unroll
      for (int j = 0; j < 8; ++j) {
        int k = s * 8 + j;
        float v = wl[(k & 255) * 9 + (k >> 8)];
        o.b8[j] = (int8_t)((v > 0.f) - (v < 0.f));
      }
      ((ull*)(wbp + (size_t)n * 2304))[s] = o.u;
    }
    return;
  }
  // bin_x: LDS transpose tile (64 m x 64 c)
  int idx = bid - 513;                         // < 3136
  const int mt = idx % 784, ct = idx / 784;
  __shared__ int8_t sh[64][68];
  const int tl = t & 63, th = t >> 6;
#pragma unroll
  for (int i = 0; i < 16; ++i) {
    int cl = th + i * 4;
    int c = ct * 64 + cl;
    int m = mt * 64 + tl;
    int b = m / HW, p = m - b * HW;
    float v = x[((size_t)b * 256 + c) * HW + p];   // coalesced along p
    sh[tl][cl] = (int8_t)((v > 0.f) - (v < 0.f));
  }
  __syncthreads();
#pragma unroll
  for (int i = 0; i < 16; ++i) {
    int ml = th + i * 4;
    xb[(size_t)(mt * 64 + ml) * 256 + ct * 64 + tl] = sh[ml][tl];
  }
}

// ---------------------------------------------------------------- conv (MFMA)
// xb [M][256] i8 NHWC, wb [256][2304] i8 -> y [M][256] i16 NHWC
// + stats via 32-bucket ull atomics; last finishing block computes params.
// [conv body R6 VERBATIM — 41.4us, MfmaUtil 26%, 0 bank conflicts]
__global__ __launch_bounds__(256, 2) void bconv_mfma(
    const int8_t* __restrict__ xb, const int8_t* __restrict__ wb,
    int16_t* __restrict__ y, ull* __restrict__ stats,
    unsigned* __restrict__ ctr, const float* __restrict__ gamma,
    float* __restrict__ params, const int8_t* __restrict__ zp) {
  __shared__ int8_t lds[2][32768];              // per buffer A 16KB | B 16KB
  const int tid = threadIdx.x;
  const int lane = tid & 63;
  const int wv = tid >> 6;                      // 4 waves
  const int wm = wv >> 1, wn = wv & 1;          // 2x2 wave grid, 64x64 each
  const int l15 = lane & 15;
  const int l4 = lane >> 4;

  // XCD swizzle: 784 = 8*98 exactly; consecutive mtiles per XCD
  int bid = blockIdx.x;
  int nb = (bid & 7) * (NBLK / 8) + (bid >> 3);
  const int mtile = nb >> 1, ntile = nb & 1;
  const int m0 = mtile * BM, n0 = ntile * BN;

  // staging precompute: call j (0..3), lane's row r = wv*32+j*8+(lane>>3);
  // r&7 == lane>>3 -> pre-swizzle source offset is call-independent.
  // LDS 16B-slot (lane&7) of row r holds global chunk ((lane&7)^(r&7)).
  const int soff = ((lane & 7) ^ (lane >> 3)) << 4;
  int pyv[4], pxv[4], ldso[4];
  size_t pixb[4];
  const int8_t* wsrc[4];
#pragma unroll
  for (int j = 0; j < 4; ++j) {
    int r = wv * 32 + j * 8 + (lane >> 3);
    int m = m0 + r;
    int b = m / HW;
    int p = m - b * HW;
    pyv[j] = p / 28;
    pxv[j] = p - pyv[j] * 28;
    pixb[j] = (size_t)b * HW;
    wsrc[j] = wb + (size_t)(n0 + r) * 2304 + soff;
    ldso[j] = (wv * 32 + j * 8) * 128;          // wave-uniform LDS base
  }

  i32x4 acc[4][4];
#pragma unroll
  for (int a = 0; a < 4; ++a)
#pragma unroll
    for (int b = 0; b < 4; ++b) acc[a][b] = (i32x4){0, 0, 0, 0};

  // unit u = tap*2 + h : tap = u>>1 (0..8), K-half h = u&1 (channel 128-block)
  // STAGE = exactly 8 gload16 per thread (A 4 + B 4) -> vmcnt granularity 8.
  auto STAGE = [&](int8_t* base, int unit) {
    const int tap = unit >> 1;
    const int coff = (unit & 1) << 7;
    const int dy = tap / 3 - 1, dx = tap % 3 - 1;
#pragma unroll
    for (int j = 0; j < 4; ++j) {
      int yy = pyv[j] + dy, xx = pxv[j] + dx;
      const int8_t* sa = ((unsigned)yy < 28u && (unsigned)xx < 28u)
              ? xb + ((pixb[j] + yy * 28 + xx) << 8) + coff + soff
              : zp + soff;
      gload16(sa, base + ldso[j]);                            // A half-tile
      gload16(wsrc[j] + (unit << 7), base + 16384 + ldso[j]); // B half-tile
    }
  };

  auto COMPUTE = [&](const int8_t* base) {
#pragma unroll
    for (int cc = 0; cc < 2; ++cc) {            // K chunks of 64 within half
      i32x4 af[4], bf[4];
      const int bc = cc * 4 + l4;               // 16B block index 0..7
#pragma unroll
      for (int rb = 0; rb < 4; ++rb) {
        int row = wm * 64 + rb * 16 + l15;
        af[rb] = *(const i32x4*)(base + row * 128 + ((bc ^ (row & 7)) << 4));
      }
#pragma unroll
      for (int nf = 0; nf < 4; ++nf) {
        int row = wn * 64 + nf * 16 + l15;
        bf[nf] = *(const i32x4*)(base + 16384 + row * 128 + ((bc ^ (row & 7)) << 4));
      }
      __builtin_amdgcn_s_setprio(1);            // T5: favor MFMA cluster
#pragma unroll
      for (int nf = 0; nf < 4; ++nf)
#pragma unroll
        for (int rb = 0; rb < 4; ++rb)
          acc[nf][rb] = __builtin_amdgcn_mfma_i32_16x16x64_i8(af[rb], bf[nf],
                                                              acc[nf][rb], 0, 0, 0);
      __builtin_amdgcn_s_setprio(0);
    }
  };

  // Counted-vmcnt pipeline (T3+T4): prefetch depth 2, never drain in steady
  // state. Per unit: COMPUTE(u); BAR; STAGE(u+2 into freed buf); VM8; BAR.
  STAGE(lds[0], 0);
  STAGE(lds[1], 1);                             // 16 outstanding
  VM8();                                        // unit 0 landed (in-order)
  BAR();
#pragma unroll
  for (int u = 0; u < 18; u += 2) {
    COMPUTE(lds[0]);                            // unit u
    BAR();                                      // done reading lds[0]
    if (u + 2 < 18) { STAGE(lds[0], u + 2); VM8(); BAR(); }
    else            { VM0(); BAR(); }           // u=16: wait unit 17
    COMPUTE(lds[1]);                            // unit u+1
    BAR();                                      // done reading lds[1]
    if (u + 3 < 18) { STAGE(lds[1], u + 3); VM8(); BAR(); }
  }

  // epilogue: store y (i16 NHWC) + exact per-channel stats via atomics
  int sum_l[4] = {0, 0, 0, 0}, sq_l[4] = {0, 0, 0, 0};
#pragma unroll
  for (int nf = 0; nf < 4; ++nf) {
    const int n = n0 + wn * 64 + nf * 16 + l15;   // C/D: col = lane&15 (m89)
#pragma unroll
    for (int rb = 0; rb < 4; ++rb) {
      const int mb = m0 + wm * 64 + rb * 16 + l4 * 4;  // row = (lane>>4)*4 + j
#pragma unroll
      for (int j = 0; j < 4; ++j) {
        int v = acc[nf][rb][j];
        y[(size_t)(mb + j) * 256 + n] = (int16_t)v;
        sum_l[nf] += v;
        sq_l[nf] += v * v;                        // <= 16*2304^2, fits i32
      }
    }
  }
  const int bucket = bid & 31;
#pragma unroll
  for (int nf = 0; nf < 4; ++nf) {
    int s = sum_l[nf], q = sq_l[nf];
    s += __shfl_xor(s, 16); q += __shfl_xor(q, 16);
    s += __shfl_xor(s, 32); q += __shfl_xor(q, 32);
    if (lane < 16) {
      int n = n0 + wn * 64 + nf * 16 + lane;
      ull* slot = stats + ((size_t)(bucket * 256 + n) << 1);
      atomicAdd(slot, (ull)(long long)s);         // exact: integer wrap-safe
      atomicAdd(slot + 1, (ull)(long long)q);
    }
  }

  // fused final reduction: last finishing block computes BN params.
  // islast flag broadcast through lds[0][0] (dead after K-loop) — LDS stays
  // exactly 64KB -> 2 blocks/CU (R17's extra __shared__ word broke this).
  __threadfence();                               // stats atomics visible
  __syncthreads();                               // all lanes past LDS use
  volatile int* flag = (volatile int*)&lds[0][0];
  if (tid == 0) *flag = (atomicAdd(ctr, 1u) == NBLK - 1) ? 1 : 0;
  __syncthreads();
  if (*flag) {
    __threadfence();
    const int c = tid;                           // one channel per thread
    long long s = 0, q = 0;
#pragma unroll
    for (int k = 0; k < 32; ++k) {
      s += (long long)__hip_atomic_load(stats + ((size_t)(k * 256 + c) << 1),
                                        __ATOMIC_RELAXED, __HIP_MEMORY_SCOPE_AGENT);
      q += (long long)__hip_atomic_load(stats + ((size_t)(k * 256 + c) << 1) + 1,
                                        __ATOMIC_RELAXED, __HIP_MEMORY_SCOPE_AGENT);
    }
    double mean = (double)s / (double)MTOT;
    double var = (double)q / (double)MTOT - mean * mean;
    params[c * 2 + 0] = (float)mean;
    params[c * 2 + 1] = (float)((double)gamma[c] / sqrt(var + 1e-5));
    // re-zero state for the next graph replay (prep also re-zeros)
#pragma unroll
    for (int k = 0; k < 32; ++k) {
      __hip_atomic_store(stats + ((size_t)(k * 256 + c) << 1), 0ull,
                         __ATOMIC_RELAXED, __HIP_MEMORY_SCOPE_AGENT);
      __hip_atomic_store(stats + ((size_t)(k * 256 + c) << 1) + 1, 0ull,
                         __ATOMIC_RELAXED, __HIP_MEMORY_SCOPE_AGENT);
    }
    if (tid == 0)
      __hip_atomic_store(ctr, 0u, __ATOMIC_RELAXED, __HIP_MEMORY_SCOPE_AGENT);
  }
}

// ---------------------------------------------------------------- binarize mid
// xb = sign((y - mean)*inv + beta)   (bias cancels in BN)
__global__ __launch_bounds__(256) void bin_mid(const int16_t* __restrict__ y,
                                               const float* __restrict__ params,
                                               const float* __restrict__ beta,
                                               int8_t* __restrict__ xb) {
  size_t i = ((size_t)blockIdx.x * 256 + threadIdx.x) * 8;
  shortx8 v = *(const shortx8*)(y + i);
  int cb = (int)(i & 255);
  union { int8_t b[8]; ull u; } o;
#pragma unroll
  for (int j = 0; j < 8; ++j) {
    int c = cb + j;
    float z = ((float)v[j] - params[c * 2]) * params[c * 2 + 1] + beta[c];
    o.b[j] = (int8_t)((z > 0.f) - (z < 0.f));
  }
  *(ull*)(xb + i) = o.u;
}

// ---------------------------------------------------------------- BN2 + resid
// out NCHW f32 = (y2 - mean)*inv + beta + x. Thread owns one m x 32-channel
// cache line of y (4x shortx8); params scalar-uniform; x/out lane-coalesced.
__global__ __launch_bounds__(256) void bn_residual(const int16_t* __restrict__ y,
                                                   const float* __restrict__ params,
                                                   const float* __restrict__ beta,
                                                   const float* __restrict__ x,
                                                   float* __restrict__ out) {
  const int t = threadIdx.x;
  const int m = blockIdx.x * 256 + t;
  const int c0 = blockIdx.y * 32;
  const int b = m / HW, p = m - b * HW;
  const int16_t* yp = y + (size_t)m * 256 + c0;
  shortx8 v0 = *(const shortx8*)(yp);
  shortx8 v1 = *(const shortx8*)(yp + 8);
  shortx8 v2 = *(const shortx8*)(yp + 16);
  shortx8 v3 = *(const shortx8*)(yp + 24);
  const size_t xbase = ((size_t)b * 256 + c0) * HW + p;
#pragma unroll
  for (int j = 0; j < 8; ++j) {
#pragma unroll
    for (int g = 0; g < 4; ++g) {
      int c = c0 + g * 8 + j;
      short sv = (g == 0) ? v0[j] : (g == 1) ? v1[j] : (g == 2) ? v2[j] : v3[j];
      float z = ((float)sv - params[c * 2]) * params[c * 2 + 1] + beta[c];
      size_t oi = xbase + (size_t)(g * 8 + j) * HW;
      out[oi] = z + x[oi];
    }
  }
}

// ---------------------------------------------------------------- launch
extern "C" void kernel_launch(void* const* d_in, const int* in_sizes, int n_in,
                              void* d_out, int out_size, void* d_ws, size_t ws_size,
                              hipStream_t stream) {
  const float* x      = (const float*)d_in[0];
  const float* w1     = (const float*)d_in[1];
  const float* gamma1 = (const float*)d_in[3];
  const float* beta1  = (const float*)d_in[4];
  const float* w2     = (const float*)d_in[5];
  const float* gamma2 = (const float*)d_in[7];
  const float* beta2  = (const float*)d_in[8];
  float* out = (float*)d_out;

  // ws layout (bytes):
  char* ws = (char*)d_ws;
  int8_t*   zp      = (int8_t*)ws;                      //        0 : 4096 zero page
  int8_t*   wb1     = (int8_t*)(ws + 4096);             //   589824
  int8_t*   wb2     = (int8_t*)(ws + 593920);           //   589824
  float*    params1 = (float*)(ws + 1183744);           //     2048
  float*    params2 = (float*)(ws + 1185792);           //     2048
  ull*      stats1  = (ull*)(ws + 1187840);             //   131072 (32 buckets)
  ull*      stats2  = (ull*)(ws + 1318912);             //   131072
  unsigned* ctrs    = (unsigned*)(ws + 1449984);        //     4096 (2 used)
  int8_t*   xb      = (int8_t*)(ws + 2793472);          // 12845056 (conv input)
  int16_t*  yb      = (int16_t*)(ws + 15638528);        // 25690112 (y1/y2 reused)
  if (ws_size < 41328640ull) return;                    // need ~39.4 MiB scratch

  prep<<<3649, 256, 0, stream>>>(w1, w2, wb1, wb2, (floatx4*)zp,
                                 (int4v*)stats1, ctrs, x, xb);
  bconv_mfma<<<NBLK, 256, 0, stream>>>(xb, wb1, yb, stats1, ctrs + 0,
                                       gamma1, params1, zp);
  bin_mid<<<6272, 256, 0, stream>>>(yb, params1, beta1, xb);
  bconv_mfma<<<NBLK, 256, 0, stream>>>(xb, wb2, yb, stats2, ctrs + 1,
                                       gamma2, params2, zp);
  bn_residual<<<dim3(196, 8), 256, 0, stream>>>(yb, params2, beta2, x, out);
}

// Round 19
// 141.976 us; speedup vs baseline: 2.4765x; 2.3091x over previous
//
#include <hip/hip_runtime.h>
#include <stdint.h>

// Binary BasicBlock: x ->(sign) conv1 ->BN1 ->(sign) conv2 ->BN2 -> +x
// B=64, C=256, H=W=28.  M = 64*784 = 50176 output pixels, N = 256, K = 9*256.
// Convs as exact i8 MFMA implicit-GEMM (binarized {-1,0,1}, int accum <= 2304
// -> bit-exact vs f32). Conv biases cancel in training-mode BN -> dropped.
//
// R19 = R15 (proven 140.8us best) + R16-proven 32-bucket atomic stats:
// conv epilogue does ull atomicAdd into 32 buckets (NO threadfence — R18
// showed per-block agent fences serialize the chip); bn_params = 1 block
// reading 16KB instead of 256 blocks reading 1.6MB partials.
// Conv body = R6 VERBATIM (best of 12 structural attempts).

#define HW    784
#define MTOT  50176
#define BM    128
#define BN    128
#define NBLK  784          // (MTOT/128) * (256/128)

typedef int   i32x4  __attribute__((ext_vector_type(4)));
typedef int   int4v  __attribute__((ext_vector_type(4)));
typedef short shortx8 __attribute__((ext_vector_type(8)));
typedef float floatx4 __attribute__((ext_vector_type(4)));
typedef unsigned long long ull;

typedef __attribute__((address_space(1))) const void gvoid_t;
typedef __attribute__((address_space(3))) void       lvoid_t;

__device__ __forceinline__ void gload16(const void* g, void* l) {
  // async global->LDS, 16B/lane; LDS dest = wave-uniform base + lane*16
  __builtin_amdgcn_global_load_lds((gvoid_t*)g, (lvoid_t*)l, 16, 0, 0);
}

#define BAR() __builtin_amdgcn_s_barrier()
#define VM8() asm volatile("s_waitcnt vmcnt(8)" ::: "memory")
#define VM0() asm volatile("s_waitcnt vmcnt(0)" ::: "memory")

// ---------------------------------------------------------------- prep
// bid 0: zero page + stats buckets (both convs, 256KB); 1..512: w binarize
// (one n-row per block, LDS-staged); 513..3648: bin_x transpose.
__global__ __launch_bounds__(256) void prep(const float* __restrict__ w1,
                                            const float* __restrict__ w2,
                                            int8_t* __restrict__ wb1,
                                            int8_t* __restrict__ wb2,
                                            floatx4* __restrict__ zp,
                                            int4v* __restrict__ statsz, // 262144B
                                            const float* __restrict__ x,
                                            int8_t* __restrict__ xb) {
  const int bid = blockIdx.x;
  const int t = threadIdx.x;
  if (bid == 0) {
    zp[t] = (floatx4){0.f, 0.f, 0.f, 0.f};
#pragma unroll
    for (int k = 0; k < 64; ++k) statsz[t + k * 256] = (int4v){0, 0, 0, 0};
    return;
  }
  if (bid < 513) {
    // w OIHW [256][256][3][3] -> wb [n][k], k = tap*256 + c (tap = ky*3+kx).
    int base = bid - 1;                        // 0..511
    const float* w = (base < 256) ? w1 : w2;
    int8_t* wbp = (base < 256) ? wb1 : wb2;
    int n = base & 255;
    __shared__ float wl[2304];
    for (int i = t; i < 2304; i += 256) wl[i] = w[(size_t)n * 2304 + i];
    __syncthreads();
    for (int s = t; s < 288; s += 256) {
      union { int8_t b8[8]; ull u; } o;
#pragma unroll
      for (int j = 0; j < 8; ++j) {
        int k = s * 8 + j;
        float v = wl[(k & 255) * 9 + (k >> 8)];
        o.b8[j] = (int8_t)((v > 0.f) - (v < 0.f));
      }
      ((ull*)(wbp + (size_t)n * 2304))[s] = o.u;
    }
    return;
  }
  // bin_x: LDS transpose tile (64 m x 64 c)
  int idx = bid - 513;                         // < 3136
  const int mt = idx % 784, ct = idx / 784;
  __shared__ int8_t sh[64][68];
  const int tl = t & 63, th = t >> 6;
#pragma unroll
  for (int i = 0; i < 16; ++i) {
    int cl = th + i * 4;
    int c = ct * 64 + cl;
    int m = mt * 64 + tl;
    int b = m / HW, p = m - b * HW;
    float v = x[((size_t)b * 256 + c) * HW + p];   // coalesced along p
    sh[tl][cl] = (int8_t)((v > 0.f) - (v < 0.f));
  }
  __syncthreads();
#pragma unroll
  for (int i = 0; i < 16; ++i) {
    int ml = th + i * 4;
    xb[(size_t)(mt * 64 + ml) * 256 + ct * 64 + tl] = sh[ml][tl];
  }
}

// ---------------------------------------------------------------- conv (MFMA)
// xb [M][256] i8 NHWC, wb [256][2304] i8 -> y [M][256] i16 NHWC
// + per-channel stats via 32-bucket ull atomicAdd (exact, wrap-safe, NO fence)
// [conv body R6 VERBATIM — 41.4us, MfmaUtil 26%, 0 bank conflicts]
__global__ __launch_bounds__(256, 2) void bconv_mfma(
    const int8_t* __restrict__ xb, const int8_t* __restrict__ wb,
    int16_t* __restrict__ y, ull* __restrict__ stats,
    const int8_t* __restrict__ zp) {
  __shared__ int8_t lds[2][32768];              // per buffer A 16KB | B 16KB
  const int tid = threadIdx.x;
  const int lane = tid & 63;
  const int wv = tid >> 6;                      // 4 waves
  const int wm = wv >> 1, wn = wv & 1;          // 2x2 wave grid, 64x64 each
  const int l15 = lane & 15;
  const int l4 = lane >> 4;

  // XCD swizzle: 784 = 8*98 exactly; consecutive mtiles per XCD
  int bid = blockIdx.x;
  int nb = (bid & 7) * (NBLK / 8) + (bid >> 3);
  const int mtile = nb >> 1, ntile = nb & 1;
  const int m0 = mtile * BM, n0 = ntile * BN;

  // staging precompute: call j (0..3), lane's row r = wv*32+j*8+(lane>>3);
  // r&7 == lane>>3 -> pre-swizzle source offset is call-independent.
  // LDS 16B-slot (lane&7) of row r holds global chunk ((lane&7)^(r&7)).
  const int soff = ((lane & 7) ^ (lane >> 3)) << 4;
  int pyv[4], pxv[4], ldso[4];
  size_t pixb[4];
  const int8_t* wsrc[4];
#pragma unroll
  for (int j = 0; j < 4; ++j) {
    int r = wv * 32 + j * 8 + (lane >> 3);
    int m = m0 + r;
    int b = m / HW;
    int p = m - b * HW;
    pyv[j] = p / 28;
    pxv[j] = p - pyv[j] * 28;
    pixb[j] = (size_t)b * HW;
    wsrc[j] = wb + (size_t)(n0 + r) * 2304 + soff;
    ldso[j] = (wv * 32 + j * 8) * 128;          // wave-uniform LDS base
  }

  i32x4 acc[4][4];
#pragma unroll
  for (int a = 0; a < 4; ++a)
#pragma unroll
    for (int b = 0; b < 4; ++b) acc[a][b] = (i32x4){0, 0, 0, 0};

  // unit u = tap*2 + h : tap = u>>1 (0..8), K-half h = u&1 (channel 128-block)
  // STAGE = exactly 8 gload16 per thread (A 4 + B 4) -> vmcnt granularity 8.
  auto STAGE = [&](int8_t* base, int unit) {
    const int tap = unit >> 1;
    const int coff = (unit & 1) << 7;
    const int dy = tap / 3 - 1, dx = tap % 3 - 1;
#pragma unroll
    for (int j = 0; j < 4; ++j) {
      int yy = pyv[j] + dy, xx = pxv[j] + dx;
      const int8_t* sa = ((unsigned)yy < 28u && (unsigned)xx < 28u)
              ? xb + ((pixb[j] + yy * 28 + xx) << 8) + coff + soff
              : zp + soff;
      gload16(sa, base + ldso[j]);                            // A half-tile
      gload16(wsrc[j] + (unit << 7), base + 16384 + ldso[j]); // B half-tile
    }
  };

  auto COMPUTE = [&](const int8_t* base) {
#pragma unroll
    for (int cc = 0; cc < 2; ++cc) {            // K chunks of 64 within half
      i32x4 af[4], bf[4];
      const int bc = cc * 4 + l4;               // 16B block index 0..7
#pragma unroll
      for (int rb = 0; rb < 4; ++rb) {
        int row = wm * 64 + rb * 16 + l15;
        af[rb] = *(const i32x4*)(base + row * 128 + ((bc ^ (row & 7)) << 4));
      }
#pragma unroll
      for (int nf = 0; nf < 4; ++nf) {
        int row = wn * 64 + nf * 16 + l15;
        bf[nf] = *(const i32x4*)(base + 16384 + row * 128 + ((bc ^ (row & 7)) << 4));
      }
      __builtin_amdgcn_s_setprio(1);            // T5: favor MFMA cluster
#pragma unroll
      for (int nf = 0; nf < 4; ++nf)
#pragma unroll
        for (int rb = 0; rb < 4; ++rb)
          acc[nf][rb] = __builtin_amdgcn_mfma_i32_16x16x64_i8(af[rb], bf[nf],
                                                              acc[nf][rb], 0, 0, 0);
      __builtin_amdgcn_s_setprio(0);
    }
  };

  // Counted-vmcnt pipeline (T3+T4): prefetch depth 2, never drain in steady
  // state. Per unit: COMPUTE(u); BAR; STAGE(u+2 into freed buf); VM8; BAR.
  STAGE(lds[0], 0);
  STAGE(lds[1], 1);                             // 16 outstanding
  VM8();                                        // unit 0 landed (in-order)
  BAR();
#pragma unroll
  for (int u = 0; u < 18; u += 2) {
    COMPUTE(lds[0]);                            // unit u
    BAR();                                      // done reading lds[0]
    if (u + 2 < 18) { STAGE(lds[0], u + 2); VM8(); BAR(); }
    else            { VM0(); BAR(); }           // u=16: wait unit 17
    COMPUTE(lds[1]);                            // unit u+1
    BAR();                                      // done reading lds[1]
    if (u + 3 < 18) { STAGE(lds[1], u + 3); VM8(); BAR(); }
  }

  // epilogue: store y (i16 NHWC) + exact per-channel stats via atomics
  int sum_l[4] = {0, 0, 0, 0}, sq_l[4] = {0, 0, 0, 0};
#pragma unroll
  for (int nf = 0; nf < 4; ++nf) {
    const int n = n0 + wn * 64 + nf * 16 + l15;   // C/D: col = lane&15 (m89)
#pragma unroll
    for (int rb = 0; rb < 4; ++rb) {
      const int mb = m0 + wm * 64 + rb * 16 + l4 * 4;  // row = (lane>>4)*4 + j
#pragma unroll
      for (int j = 0; j < 4; ++j) {
        int v = acc[nf][rb][j];
        y[(size_t)(mb + j) * 256 + n] = (int16_t)v;
        sum_l[nf] += v;
        sq_l[nf] += v * v;                        // <= 16*2304^2, fits i32
      }
    }
  }
  const int bucket = bid & 31;
#pragma unroll
  for (int nf = 0; nf < 4; ++nf) {
    int s = sum_l[nf], q = sq_l[nf];
    s += __shfl_xor(s, 16); q += __shfl_xor(q, 16);
    s += __shfl_xor(s, 32); q += __shfl_xor(q, 32);
    if (lane < 16) {
      int n = n0 + wn * 64 + nf * 16 + lane;
      ull* slot = stats + ((size_t)(bucket * 256 + n) << 1);
      atomicAdd(slot, (ull)(long long)s);         // exact: integer wrap-safe
      atomicAdd(slot + 1, (ull)(long long)q);     // device-scope by default
    }
  }
}

// ---------------------------------------------------------------- BN params
// sum 32 buckets -> mean & gamma/sqrt(var+eps); re-zero buckets (2nd layer;
// prep also zeroes each launch). One block, one channel per thread.
__global__ __launch_bounds__(256) void bn_params(ull* __restrict__ stats,
                                                 const float* __restrict__ gamma,
                                                 float* __restrict__ params) {
  const int c = threadIdx.x;
  long long s = 0, q = 0;
#pragma unroll
  for (int k = 0; k < 32; ++k) {
    s += (long long)stats[(size_t)(k * 256 + c) * 2 + 0];
    q += (long long)stats[(size_t)(k * 256 + c) * 2 + 1];
  }
  double mean = (double)s / (double)MTOT;
  double var = (double)q / (double)MTOT - mean * mean;
  params[c * 2 + 0] = (float)mean;
  params[c * 2 + 1] = (float)((double)gamma[c] / sqrt(var + 1e-5));
#pragma unroll
  for (int k = 0; k < 32; ++k) {
    stats[(size_t)(k * 256 + c) * 2 + 0] = 0;
    stats[(size_t)(k * 256 + c) * 2 + 1] = 0;
  }
}

// ---------------------------------------------------------------- binarize mid
// xb = sign((y - mean)*inv + beta)   (bias cancels in BN)
__global__ __launch_bounds__(256) void bin_mid(const int16_t* __restrict__ y,
                                               const float* __restrict__ params,
                                               const float* __restrict__ beta,
                                               int8_t* __restrict__ xb) {
  size_t i = ((size_t)blockIdx.x * 256 + threadIdx.x) * 8;
  shortx8 v = *(const shortx8*)(y + i);
  int cb = (int)(i & 255);
  union { int8_t b[8]; ull u; } o;
#pragma unroll
  for (int j = 0; j < 8; ++j) {
    int c = cb + j;
    float z = ((float)v[j] - params[c * 2]) * params[c * 2 + 1] + beta[c];
    o.b[j] = (int8_t)((z > 0.f) - (z < 0.f));
  }
  *(ull*)(xb + i) = o.u;
}

// ---------------------------------------------------------------- BN2 + resid
// out NCHW f32 = (y2 - mean)*inv + beta + x. Thread owns one m x 32-channel
// cache line of y (4x shortx8); params scalar-uniform; x/out lane-coalesced.
__global__ __launch_bounds__(256) void bn_residual(const int16_t* __restrict__ y,
                                                   const float* __restrict__ params,
                                                   const float* __restrict__ beta,
                                                   const float* __restrict__ x,
                                                   float* __restrict__ out) {
  const int t = threadIdx.x;
  const int m = blockIdx.x * 256 + t;
  const int c0 = blockIdx.y * 32;
  const int b = m / HW, p = m - b * HW;
  const int16_t* yp = y + (size_t)m * 256 + c0;
  shortx8 v0 = *(const shortx8*)(yp);
  shortx8 v1 = *(const shortx8*)(yp + 8);
  shortx8 v2 = *(const shortx8*)(yp + 16);
  shortx8 v3 = *(const shortx8*)(yp + 24);
  const size_t xbase = ((size_t)b * 256 + c0) * HW + p;
#pragma unroll
  for (int j = 0; j < 8; ++j) {
#pragma unroll
    for (int g = 0; g < 4; ++g) {
      int c = c0 + g * 8 + j;
      short sv = (g == 0) ? v0[j] : (g == 1) ? v1[j] : (g == 2) ? v2[j] : v3[j];
      float z = ((float)sv - params[c * 2]) * params[c * 2 + 1] + beta[c];
      size_t oi = xbase + (size_t)(g * 8 + j) * HW;
      out[oi] = z + x[oi];
    }
  }
}

// ---------------------------------------------------------------- launch
extern "C" void kernel_launch(void* const* d_in, const int* in_sizes, int n_in,
                              void* d_out, int out_size, void* d_ws, size_t ws_size,
                              hipStream_t stream) {
  const float* x      = (const float*)d_in[0];
  const float* w1     = (const float*)d_in[1];
  const float* gamma1 = (const float*)d_in[3];
  const float* beta1  = (const float*)d_in[4];
  const float* w2     = (const float*)d_in[5];
  const float* gamma2 = (const float*)d_in[7];
  const float* beta2  = (const float*)d_in[8];
  float* out = (float*)d_out;

  // ws layout (bytes):
  char* ws = (char*)d_ws;
  int8_t*   zp      = (int8_t*)ws;                      //        0 : 4096 zero page
  int8_t*   wb1     = (int8_t*)(ws + 4096);             //   589824
  int8_t*   wb2     = (int8_t*)(ws + 593920);           //   589824
  float*    params1 = (float*)(ws + 1183744);           //     2048
  float*    params2 = (float*)(ws + 1185792);           //     2048
  ull*      stats1  = (ull*)(ws + 1187840);             //   131072 (32 buckets)
  ull*      stats2  = (ull*)(ws + 1318912);             //   131072
  int8_t*   xb      = (int8_t*)(ws + 2793472);          // 12845056 (conv input)
  int16_t*  yb      = (int16_t*)(ws + 15638528);        // 25690112 (y1/y2 reused)
  if (ws_size < 41328640ull) return;                    // need ~39.4 MiB scratch

  prep<<<3649, 256, 0, stream>>>(w1, w2, wb1, wb2, (floatx4*)zp,
                                 (int4v*)stats1, x, xb);
  bconv_mfma<<<NBLK, 256, 0, stream>>>(xb, wb1, yb, stats1, zp);
  bn_params<<<1, 256, 0, stream>>>(stats1, gamma1, params1);
  bin_mid<<<6272, 256, 0, stream>>>(yb, params1, beta1, xb);
  bconv_mfma<<<NBLK, 256, 0, stream>>>(xb, wb2, yb, stats2, zp);
  bn_params<<<1, 256, 0, stream>>>(stats2, gamma2, params2);
  bn_residual<<<dim3(196, 8), 256, 0, stream>>>(yb, params2, beta2, x, out);
}

// Round 20
// 140.681 us; speedup vs baseline: 2.4993x; 1.0092x over previous
//
#include <hip/hip_runtime.h>
#include <stdint.h>

// Binary BasicBlock: x ->(sign) conv1 ->BN1 ->(sign) conv2 ->BN2 -> +x
// B=64, C=256, H=W=28.  M = 64*784 = 50176 output pixels, N = 256, K = 9*256.
// Convs as exact i8 MFMA implicit-GEMM (binarized {-1,0,1}, int accum <= 2304
// -> bit-exact vs f32). Conv biases cancel in training-mode BN -> dropped.
//
// R20 = R15 VERBATIM (measured best: 140.8us). Final configuration.
// conv = R6 body (best of 13 structural attempts; counted-vmcnt dbuf,
// 128B rows, slot^(row&7) swizzle — the only conflict-free layout).
// Stats via per-block partial stores (R19 showed atomics cost +2us/conv;
// R18 showed per-block fences serialize the chip). Tail: LDS-staged
// w-binarize, merged prep, cache-line-exact bn_residual.

#define HW    784
#define MTOT  50176
#define BM    128
#define BN    128
#define MT    392          // MTOT/BM
#define NBLK  784          // MT * (256/BN)

typedef int   i32x4  __attribute__((ext_vector_type(4)));
typedef short shortx8 __attribute__((ext_vector_type(8)));
typedef float floatx4 __attribute__((ext_vector_type(4)));
typedef unsigned long long ull;

typedef __attribute__((address_space(1))) const void gvoid_t;
typedef __attribute__((address_space(3))) void       lvoid_t;

__device__ __forceinline__ void gload16(const void* g, void* l) {
  // async global->LDS, 16B/lane; LDS dest = wave-uniform base + lane*16
  __builtin_amdgcn_global_load_lds((gvoid_t*)g, (lvoid_t*)l, 16, 0, 0);
}

#define BAR() __builtin_amdgcn_s_barrier()
#define VM8() asm volatile("s_waitcnt vmcnt(8)" ::: "memory")
#define VM0() asm volatile("s_waitcnt vmcnt(0)" ::: "memory")

// ---------------------------------------------------------------- prep
// bid 0: zero page; 1..512: w binarize (one n-row per block, LDS-staged);
// 513..3648: bin_x transpose (x NCHW f32 -> xb NHWC i8).
__global__ __launch_bounds__(256) void prep(const float* __restrict__ w1,
                                            const float* __restrict__ w2,
                                            int8_t* __restrict__ wb1,
                                            int8_t* __restrict__ wb2,
                                            floatx4* __restrict__ zp,
                                            const float* __restrict__ x,
                                            int8_t* __restrict__ xb) {
  const int bid = blockIdx.x;
  const int t = threadIdx.x;
  if (bid == 0) { zp[t] = (floatx4){0.f, 0.f, 0.f, 0.f}; return; }
  if (bid < 513) {
    // w OIHW [256][256][3][3] -> wb [n][k], k = tap*256 + c (tap = ky*3+kx).
    // Read w[n][*] coalesced (2304 contiguous f32), write wb row as 288 ull.
    int base = bid - 1;                        // 0..511
    const float* w = (base < 256) ? w1 : w2;
    int8_t* wbp = (base < 256) ? wb1 : wb2;
    int n = base & 255;
    __shared__ float wl[2304];
    for (int i = t; i < 2304; i += 256) wl[i] = w[(size_t)n * 2304 + i];
    __syncthreads();
    for (int s = t; s < 288; s += 256) {
      union { int8_t b8[8]; ull u; } o;
#pragma unroll
      for (int j = 0; j < 8; ++j) {
        int k = s * 8 + j;
        float v = wl[(k & 255) * 9 + (k >> 8)];
        o.b8[j] = (int8_t)((v > 0.f) - (v < 0.f));
      }
      ((ull*)(wbp + (size_t)n * 2304))[s] = o.u;
    }
    return;
  }
  // bin_x: LDS transpose tile (64 m x 64 c)
  int idx = bid - 513;                         // < 3136
  const int mt = idx % 784, ct = idx / 784;
  __shared__ int8_t sh[64][68];
  const int tl = t & 63, th = t >> 6;
#pragma unroll
  for (int i = 0; i < 16; ++i) {
    int cl = th + i * 4;
    int c = ct * 64 + cl;
    int m = mt * 64 + tl;
    int b = m / HW, p = m - b * HW;
    float v = x[((size_t)b * 256 + c) * HW + p];   // coalesced along p
    sh[tl][cl] = (int8_t)((v > 0.f) - (v < 0.f));
  }
  __syncthreads();
#pragma unroll
  for (int i = 0; i < 16; ++i) {
    int ml = th + i * 4;
    xb[(size_t)(mt * 64 + ml) * 256 + ct * 64 + tl] = sh[ml][tl];
  }
}

// ---------------------------------------------------------------- conv (MFMA)
// xb [M][256] i8 NHWC, wb [256][2304] i8 -> y [M][256] i16 NHWC
// + per-(mtile,wave_m) channel partial sum / sumsq (exact i32, no atomics)
// [R6 VERBATIM — 41.4us, MfmaUtil 26%, 0 bank conflicts]
__global__ __launch_bounds__(256, 2) void bconv_mfma(
    const int8_t* __restrict__ xb, const int8_t* __restrict__ wb,
    int16_t* __restrict__ y, int* __restrict__ ssum, int* __restrict__ ssq,
    const int8_t* __restrict__ zp) {
  __shared__ int8_t lds[2][32768];              // per buffer A 16KB | B 16KB
  const int tid = threadIdx.x;
  const int lane = tid & 63;
  const int wv = tid >> 6;                      // 4 waves
  const int wm = wv >> 1, wn = wv & 1;          // 2x2 wave grid, 64x64 each
  const int l15 = lane & 15;
  const int l4 = lane >> 4;

  // XCD swizzle: 784 = 8*98 exactly; consecutive mtiles per XCD
  int bid = blockIdx.x;
  int nb = (bid & 7) * (NBLK / 8) + (bid >> 3);
  const int mtile = nb >> 1, ntile = nb & 1;
  const int m0 = mtile * BM, n0 = ntile * BN;

  // staging precompute: call j (0..3), lane's row r = wv*32+j*8+(lane>>3);
  // r&7 == lane>>3 -> pre-swizzle source offset is call-independent.
  // LDS 16B-slot (lane&7) of row r holds global chunk ((lane&7)^(r&7)).
  const int soff = ((lane & 7) ^ (lane >> 3)) << 4;
  int pyv[4], pxv[4], ldso[4];
  size_t pixb[4];
  const int8_t* wsrc[4];
#pragma unroll
  for (int j = 0; j < 4; ++j) {
    int r = wv * 32 + j * 8 + (lane >> 3);
    int m = m0 + r;
    int b = m / HW;
    int p = m - b * HW;
    pyv[j] = p / 28;
    pxv[j] = p - pyv[j] * 28;
    pixb[j] = (size_t)b * HW;
    wsrc[j] = wb + (size_t)(n0 + r) * 2304 + soff;
    ldso[j] = (wv * 32 + j * 8) * 128;          // wave-uniform LDS base
  }

  i32x4 acc[4][4];
#pragma unroll
  for (int a = 0; a < 4; ++a)
#pragma unroll
    for (int b = 0; b < 4; ++b) acc[a][b] = (i32x4){0, 0, 0, 0};

  // unit u = tap*2 + h : tap = u>>1 (0..8), K-half h = u&1 (channel 128-block)
  // STAGE = exactly 8 gload16 per thread (A 4 + B 4) -> vmcnt granularity 8.
  auto STAGE = [&](int8_t* base, int unit) {
    const int tap = unit >> 1;
    const int coff = (unit & 1) << 7;
    const int dy = tap / 3 - 1, dx = tap % 3 - 1;
#pragma unroll
    for (int j = 0; j < 4; ++j) {
      int yy = pyv[j] + dy, xx = pxv[j] + dx;
      const int8_t* sa = ((unsigned)yy < 28u && (unsigned)xx < 28u)
              ? xb + ((pixb[j] + yy * 28 + xx) << 8) + coff + soff
              : zp + soff;
      gload16(sa, base + ldso[j]);                            // A half-tile
      gload16(wsrc[j] + (unit << 7), base + 16384 + ldso[j]); // B half-tile
    }
  };

  auto COMPUTE = [&](const int8_t* base) {
#pragma unroll
    for (int cc = 0; cc < 2; ++cc) {            // K chunks of 64 within half
      i32x4 af[4], bf[4];
      const int bc = cc * 4 + l4;               // 16B block index 0..7
#pragma unroll
      for (int rb = 0; rb < 4; ++rb) {
        int row = wm * 64 + rb * 16 + l15;
        af[rb] = *(const i32x4*)(base + row * 128 + ((bc ^ (row & 7)) << 4));
      }
#pragma unroll
      for (int nf = 0; nf < 4; ++nf) {
        int row = wn * 64 + nf * 16 + l15;
        bf[nf] = *(const i32x4*)(base + 16384 + row * 128 + ((bc ^ (row & 7)) << 4));
      }
      __builtin_amdgcn_s_setprio(1);            // T5: favor MFMA cluster
#pragma unroll
      for (int nf = 0; nf < 4; ++nf)
#pragma unroll
        for (int rb = 0; rb < 4; ++rb)
          acc[nf][rb] = __builtin_amdgcn_mfma_i32_16x16x64_i8(af[rb], bf[nf],
                                                              acc[nf][rb], 0, 0, 0);
      __builtin_amdgcn_s_setprio(0);
    }
  };

  // Counted-vmcnt pipeline (T3+T4): prefetch depth 2, never drain in steady
  // state. Per unit: COMPUTE(u); BAR; STAGE(u+2 into freed buf); VM8; BAR.
  STAGE(lds[0], 0);
  STAGE(lds[1], 1);                             // 16 outstanding
  VM8();                                        // unit 0 landed (in-order)
  BAR();
#pragma unroll
  for (int u = 0; u < 18; u += 2) {
    COMPUTE(lds[0]);                            // unit u
    BAR();                                      // done reading lds[0]
    if (u + 2 < 18) { STAGE(lds[0], u + 2); VM8(); BAR(); }
    else            { VM0(); BAR(); }           // u=16: wait unit 17
    COMPUTE(lds[1]);                            // unit u+1
    BAR();                                      // done reading lds[1]
    if (u + 3 < 18) { STAGE(lds[1], u + 3); VM8(); BAR(); }
  }

  // epilogue: store y (i16 NHWC) + exact per-channel partials
  int sum_l[4] = {0, 0, 0, 0}, sq_l[4] = {0, 0, 0, 0};
#pragma unroll
  for (int nf = 0; nf < 4; ++nf) {
    const int n = n0 + wn * 64 + nf * 16 + l15;   // C/D: col = lane&15 (m89)
#pragma unroll
    for (int rb = 0; rb < 4; ++rb) {
      const int mb = m0 + wm * 64 + rb * 16 + l4 * 4;  // row = (lane>>4)*4 + j
#pragma unroll
      for (int j = 0; j < 4; ++j) {
        int v = acc[nf][rb][j];
        y[(size_t)(mb + j) * 256 + n] = (int16_t)v;
        sum_l[nf] += v;
        sq_l[nf] += v * v;                        // <= 16*2304^2, fits i32
      }
    }
  }
#pragma unroll
  for (int nf = 0; nf < 4; ++nf) {
    int s = sum_l[nf], q = sq_l[nf];
    s += __shfl_xor(s, 16); q += __shfl_xor(q, 16);
    s += __shfl_xor(s, 32); q += __shfl_xor(q, 32);
    if (lane < 16) {
      size_t off = (size_t)(mtile * 2 + wm) * 256 + (n0 + wn * 64 + nf * 16 + lane);
      ssum[off] = s;                              // unique writer per slot
      ssq[off] = q;
    }
  }
}

// ---------------------------------------------------------------- BN params
// reduce [MT*2][256] partials -> per-channel mean & gamma*rsqrt(var+eps)
__global__ __launch_bounds__(256) void bn_params(const int* __restrict__ ssum,
                                                 const int* __restrict__ ssq,
                                                 const float* __restrict__ gamma,
                                                 float* __restrict__ params) {
  const int c = blockIdx.x;
  const int t = threadIdx.x;
  long long s = 0, q = 0;
  for (int e = t; e < MT * 2; e += 256) {
    s += ssum[(size_t)e * 256 + c];
    q += ssq[(size_t)e * 256 + c];
  }
  __shared__ long long sh[8];
  for (int off = 32; off; off >>= 1) { s += __shfl_down(s, off); q += __shfl_down(q, off); }
  int wv = t >> 6;
  if ((t & 63) == 0) { sh[wv] = s; sh[wv + 4] = q; }
  __syncthreads();
  if (t == 0) {
    s = sh[0] + sh[1] + sh[2] + sh[3];
    q = sh[4] + sh[5] + sh[6] + sh[7];
    double mean = (double)s / (double)MTOT;
    double var = (double)q / (double)MTOT - mean * mean;
    params[c * 2 + 0] = (float)mean;
    params[c * 2 + 1] = (float)((double)gamma[c] / sqrt(var + 1e-5));
  }
}

// ---------------------------------------------------------------- binarize mid
// xb = sign((y - mean)*inv + beta)   (bias cancels in BN)
__global__ __launch_bounds__(256) void bin_mid(const int16_t* __restrict__ y,
                                               const float* __restrict__ params,
                                               const float* __restrict__ beta,
                                               int8_t* __restrict__ xb) {
  size_t i = ((size_t)blockIdx.x * 256 + threadIdx.x) * 8;
  shortx8 v = *(const shortx8*)(y + i);
  int cb = (int)(i & 255);
  union { int8_t b[8]; ull u; } o;
#pragma unroll
  for (int j = 0; j < 8; ++j) {
    int c = cb + j;
    float z = ((float)v[j] - params[c * 2]) * params[c * 2 + 1] + beta[c];
    o.b[j] = (int8_t)((z > 0.f) - (z < 0.f));
  }
  *(ull*)(xb + i) = o.u;
}

// ---------------------------------------------------------------- BN2 + resid
// out NCHW f32 = (y2 - mean)*inv + beta + x.
// Thread owns one m x 32-channel cache line of y (4x shortx8 = 64B, each 64B
// line consumed exactly once); params/beta wave-uniform scalar loads; x/out
// reads/writes lane-coalesced 256B/wave. No LDS bounce.
__global__ __launch_bounds__(256) void bn_residual(const int16_t* __restrict__ y,
                                                   const float* __restrict__ params,
                                                   const float* __restrict__ beta,
                                                   const float* __restrict__ x,
                                                   float* __restrict__ out) {
  const int t = threadIdx.x;
  const int m = blockIdx.x * 256 + t;
  const int c0 = blockIdx.y * 32;
  const int b = m / HW, p = m - b * HW;
  const int16_t* yp = y + (size_t)m * 256 + c0;
  shortx8 v0 = *(const shortx8*)(yp);
  shortx8 v1 = *(const shortx8*)(yp + 8);
  shortx8 v2 = *(const shortx8*)(yp + 16);
  shortx8 v3 = *(const shortx8*)(yp + 24);
  const size_t xbase = ((size_t)b * 256 + c0) * HW + p;
#pragma unroll
  for (int j = 0; j < 8; ++j) {
#pragma unroll
    for (int g = 0; g < 4; ++g) {
      int c = c0 + g * 8 + j;
      short sv = (g == 0) ? v0[j] : (g == 1) ? v1[j] : (g == 2) ? v2[j] : v3[j];
      float z = ((float)sv - params[c * 2]) * params[c * 2 + 1] + beta[c];
      size_t oi = xbase + (size_t)(g * 8 + j) * HW;
      out[oi] = z + x[oi];
    }
  }
}

// ---------------------------------------------------------------- launch
extern "C" void kernel_launch(void* const* d_in, const int* in_sizes, int n_in,
                              void* d_out, int out_size, void* d_ws, size_t ws_size,
                              hipStream_t stream) {
  const float* x      = (const float*)d_in[0];
  const float* w1     = (const float*)d_in[1];
  const float* gamma1 = (const float*)d_in[3];
  const float* beta1  = (const float*)d_in[4];
  const float* w2     = (const float*)d_in[5];
  const float* gamma2 = (const float*)d_in[7];
  const float* beta2  = (const float*)d_in[8];
  float* out = (float*)d_out;

  // ws layout (bytes):
  char* ws = (char*)d_ws;
  int8_t*  zp      = (int8_t*)ws;                       //        0 : 4096 zero page
  int8_t*  wb1     = (int8_t*)(ws + 4096);              //   589824
  int8_t*  wb2     = (int8_t*)(ws + 593920);            //   589824
  float*   params1 = (float*)(ws + 1183744);            //     2048
  float*   params2 = (float*)(ws + 1185792);            //     2048
  int*     ssum    = (int*)(ws + 1187840);              //   802816
  int*     ssq     = (int*)(ws + 1990656);              //   802816
  int8_t*  xb      = (int8_t*)(ws + 2793472);           // 12845056 (conv input)
  int16_t* yb      = (int16_t*)(ws + 15638528);         // 25690112 (y1/y2 reused)
  if (ws_size < 41328640ull) return;                    // need ~39.4 MiB scratch

  prep<<<3649, 256, 0, stream>>>(w1, w2, wb1, wb2, (floatx4*)zp, x, xb);
  bconv_mfma<<<NBLK, 256, 0, stream>>>(xb, wb1, yb, ssum, ssq, zp);
  bn_params<<<256, 256, 0, stream>>>(ssum, ssq, gamma1, params1);
  bin_mid<<<6272, 256, 0, stream>>>(yb, params1, beta1, xb);
  bconv_mfma<<<NBLK, 256, 0, stream>>>(xb, wb2, yb, ssum, ssq, zp);
  bn_params<<<256, 256, 0, stream>>>(ssum, ssq, gamma2, params2);
  bn_residual<<<dim3(196, 8), 256, 0, stream>>>(yb, params2, beta2, x, out);
}